// Round 4
// baseline (299.985 us; speedup 1.0000x reference)
//
#include <hip/hip_runtime.h>
#include <math.h>

// Problem constants (fixed by setup_inputs): B=16, H=W=1024.
constexpr int Wd = 1024;
constexpr int Hd = 1024;
constexpr int HW = Wd * Hd;              // 1<<20
constexpr int NPIX = 16 * HW;            // 2^24 pixels
constexpr int NGRP = NPIX / 4;           // 2^22 float4 groups
constexpr float EPSF = 1e-7f;
constexpr float INV_TOTAL = 1.0f / 16777216.0f;  // 1/(B*H*W)

constexpr int NBLK = 2048;               // 8 blocks/CU on 256 CUs
constexpr int NTHR = 256;
constexpr int NITER = NGRP / (NBLK * NTHR);  // = 8, exact, no tail
// Per-iteration group stride = NBLK*NTHR = 2^19 groups = 2^21 pixels = 2*HW:
// rem/i/j are loop-invariant; b advances by exactly 2 per iteration.

__global__ __launch_bounds__(256) void conf_loss_partial(
    const float* __restrict__ of,    // (B, 3, H, W) fp32
    const int*   __restrict__ tgt,   // (B, H, W) int32
    float*       __restrict__ partial)  // NBLK floats
{
    const float4* of4 = (const float4*)of;
    const int gid0 = blockIdx.x * NTHR + threadIdx.x;

    const int p0  = gid0 << 2;               // first pixel, iteration 0
    const int b0  = p0 >> 20;                // 0 or 1
    const int rem = p0 & (HW - 1);           // invariant across iterations
    const int i   = rem >> 10;               // row (invariant)
    const int j   = rem & (Wd - 1);          // col of first pixel (invariant)
    const float fi = (float)i;
    const float fj0 = (float)j;

    float sum = 0.0f;
    int bad = 0;                             // bit it = some pixel non-self

    // ---- Phase 1: branch-free streaming pass (fast-path assumption) ----
#pragma unroll
    for (int it = 0; it < NITER; ++it) {
        const int b = b0 + 2 * it;
        const int baseU = b * 3 * HW + rem;          // float index
        const float4 u0 = of4[(baseU          ) >> 2];
        const float4 u1 = of4[(baseU +     HW ) >> 2];
        const float4 fv = of4[(baseU + 2 * HW ) >> 2];

        // self test: floor(u0+col)==col && floor(u1+row)==row, pre-clamp.
        // (If unclamped floor equals the in-range self coord, clamp is a
        //  no-op; if not self, bit set -> phase 2 redoes it exactly.)
        bool ok =
            (floorf(u0.x + fj0)        == fj0)        &
            (floorf(u0.y + fj0 + 1.0f) == fj0 + 1.0f) &
            (floorf(u0.z + fj0 + 2.0f) == fj0 + 2.0f) &
            (floorf(u0.w + fj0 + 3.0f) == fj0 + 3.0f) &
            (floorf(u1.x + fi) == fi) & (floorf(u1.y + fi) == fi) &
            (floorf(u1.z + fi) == fi) & (floorf(u1.w + fi) == fi);
        bad |= (ok ? 0 : 1) << it;

        sum -= __logf(fv.x + EPSF) + __logf(fv.y + EPSF) +
               __logf(fv.z + EPSF) + __logf(fv.w + EPSF);
    }

    // ---- Phase 2: rare correction (taken only if some lane non-self) ----
    if (__any(bad != 0)) {
        if (bad) {
#pragma unroll
            for (int it = 0; it < NITER; ++it) {
                if ((bad >> it) & 1) {
                    const int b = b0 + 2 * it;
                    const int baseU = b * 3 * HW + rem;
                    const float4 u0 = of4[(baseU          ) >> 2];
                    const float4 u1 = of4[(baseU +     HW ) >> 2];
                    const float4 fv = of4[(baseU + 2 * HW ) >> 2];
                    const int4  tv = ((const int4*)tgt)[(b * HW + rem) >> 2];
                    const float us[4] = {u0.x, u0.y, u0.z, u0.w};
                    const float vs[4] = {u1.x, u1.y, u1.z, u1.w};
                    const float fs[4] = {fv.x, fv.y, fv.z, fv.w};
                    const int   ts[4] = {tv.x, tv.y, tv.z, tv.w};
#pragma unroll
                    for (int k = 0; k < 4; ++k) {
                        int x = (int)floorf(us[k] + (float)(j + k));
                        int y = (int)floorf(vs[k] + fi);
                        x = min(max(x, 0), Wd - 1);
                        y = min(max(y, 0), Hd - 1);
                        int t = ts[k];
                        t = (t == -1) ? 0 : t;
                        int hs = tgt[b * HW + y * Wd + x];
                        hs = (hs == -1) ? 0 : hs;
                        if (t != hs) {
                            // phase 1 added -log(f+eps); replace with
                            // -log(1-f+eps)
                            sum += __logf(fs[k] + EPSF)
                                 - __logf(1.0f - fs[k] + EPSF);
                        }
                    }
                }
            }
        }
    }

    // wave-64 reduction
#pragma unroll
    for (int off = 32; off > 0; off >>= 1)
        sum += __shfl_down(sum, off, 64);

    __shared__ float lsum[4];                // 256 threads = 4 waves
    const int lane = threadIdx.x & 63;
    const int wv   = threadIdx.x >> 6;
    if (lane == 0) lsum[wv] = sum;
    __syncthreads();
    if (threadIdx.x == 0)
        partial[blockIdx.x] = lsum[0] + lsum[1] + lsum[2] + lsum[3];
}

__global__ __launch_bounds__(256) void conf_loss_final(
    const float* __restrict__ partial, float* __restrict__ out)
{
    float s = 0.0f;
#pragma unroll
    for (int it = 0; it < NBLK / NTHR; ++it)   // 8 each
        s += partial[it * NTHR + threadIdx.x];

#pragma unroll
    for (int off = 32; off > 0; off >>= 1)
        s += __shfl_down(s, off, 64);

    __shared__ float lsum[4];
    const int lane = threadIdx.x & 63;
    const int wv   = threadIdx.x >> 6;
    if (lane == 0) lsum[wv] = s;
    __syncthreads();
    if (threadIdx.x == 0)
        out[0] = (lsum[0] + lsum[1] + lsum[2] + lsum[3]) * INV_TOTAL;
}

extern "C" void kernel_launch(void* const* d_in, const int* in_sizes, int n_in,
                              void* d_out, int out_size, void* d_ws, size_t ws_size,
                              hipStream_t stream) {
    const float* of  = (const float*)d_in[0];
    const int*   tgt = (const int*)d_in[1];
    float*       out = (float*)d_out;
    float*       partial = (float*)d_ws;     // NBLK * 4 B = 8 KB scratch

    conf_loss_partial<<<NBLK, NTHR, 0, stream>>>(of, tgt, partial);
    conf_loss_final<<<1, NTHR, 0, stream>>>(partial, out);
}